// Round 2
// baseline (4889.420 us; speedup 1.0000x reference)
//
#include <hip/hip_runtime.h>
#include <cmath>

// ---------------------------------------------------------------------------
// 2-layer tanh RNN, B=64, T=512, D=H0=H1=1024. Persistent cooperative kernel.
// Round-6 (bisect of failed round-5): round-4 verified sync skeleton
// (block-wide polls + B1/B1b/B2/B3/B4 barriers, uc/hch epilogues, ring
// protocol) with ONLY the thread-local changes kept:
//  * load_a8/fma8 split: all 8 16B A-fragments issued before any MFMA ->
//    one L3 latency per slab instead of eight serialized ones.
//  * G1 computes the h1(t-1) half BEFORE polling h0(t): its loads+MFMAs
//    hide inside the h0 wait window; h0 then costs one batched latency.
// Round-5's per-wave fine-grained polling + scr/col_sum epilogue are
// REVERTED (correctness failure, absmax 0.21 -- suspected ordering race
// between flag observation and data loads without the full-barrier drain).
// Groups (32 WGs each, cols split 32/WG):
//   G0: h0(t) = tanh(Wh0*h0(t-1) + U(t))                [K=1024]
//   G1: h1(t) = tanh(W1*[h1(t-1); h0(t)] + b1)          [K=2048]
//   G2: U(t)  = Wx*x(t) + b0   (free-runs ahead)        [K=1024]
// Sync: relaxed SYSTEM flags/data (write-through, no cache maintenance);
// producer order via __syncthreads' vmcnt(0) drain (verified rounds 2-4).
// ---------------------------------------------------------------------------

typedef unsigned short u16;
typedef unsigned int   u32;
typedef unsigned long long u64;
typedef __bf16 bf16x8 __attribute__((ext_vector_type(8)));
typedef u16    u16x8  __attribute__((ext_vector_type(8)));
typedef u16    u16x4  __attribute__((ext_vector_type(4)));
typedef float  f32x4  __attribute__((ext_vector_type(4)));

constexpr int BB = 64;
constexpr int TT = 512;
constexpr size_t SLOT   = (size_t)64 * 1024;   // elements per [64][1024] slab
constexpr size_t SLAB_B = SLOT * 2;            // 128 KB bf16 slab

constexpr size_t OFF_W0T = 262144;             // flags in [0, 256K)
constexpr size_t OFF_W1T = OFF_W0T + (size_t)1024 * 2048 * 2;
constexpr size_t OFF_R   = OFF_W1T + (size_t)1024 * 2048 * 2;

// LDS budget (dynamic): [weights <=128K][scratch 24K][hcache 4K][ucache 4K]
constexpr int LDS_REQ = 159744;   // G1: 128K + 24K + 4K = 156K  (<=160K/CU)

__device__ inline u16 f2bf(float f) { return __builtin_bit_cast(u16, (__bf16)f); }
__device__ inline float bf2f(u16 v) { return (float)__builtin_bit_cast(__bf16, v); }
__device__ inline float fast_tanh(float x) {
  x = fminf(15.f, fmaxf(-15.f, x));
  float e = __expf(2.f * x);
  return (e - 1.f) * __builtin_amdgcn_rcpf(e + 1.f);
}

// ---------------------------------------------------------------- prep kernels
__global__ void zero_flags(unsigned* f) {
  int i = blockIdx.x * 256 + threadIdx.x;
  if (i < 3 * 512 * 32) f[i] = 0;
}

__global__ void transpose_w(const float* __restrict__ W0,
                            const float* __restrict__ W1,
                            u16* __restrict__ wt_base) {
  __shared__ float tile[64][65];
  int bi  = blockIdx.x;
  int mat = bi >> 9;
  int t   = bi & 511;
  int tk = t & 31, tn = t >> 5;
  const float* W = mat ? W1 : W0;
  u16* Wt = wt_base + (size_t)mat * 1024 * 2048;
  int K0 = tk * 64, N0 = tn * 64;
  int tid = threadIdx.x;
  {
    int c4 = (tid & 15) * 4;
    int r  = tid >> 4;
    for (int i = 0; i < 4; ++i) {
      int kl = r + i * 16;
      float4 v = *(const float4*)(W + (size_t)(K0 + kl) * 1024 + N0 + c4);
      tile[kl][c4 + 0] = v.x; tile[kl][c4 + 1] = v.y;
      tile[kl][c4 + 2] = v.z; tile[kl][c4 + 3] = v.w;
    }
  }
  __syncthreads();
  {
    int nl = tid >> 3;
    int kc = (tid & 7) * 8;
    for (int pass = 0; pass < 2; ++pass) {
      int n = nl + pass * 32;
      u16x8 o;
      #pragma unroll
      for (int z = 0; z < 8; ++z) o[z] = f2bf(tile[kc + z][n]);
      *(u16x8*)(Wt + (size_t)(N0 + n) * 2048 + K0 + kc) = o;
    }
  }
}

__global__ void xconv(const float* __restrict__ x, u16* __restrict__ xb) {
  int bi = blockIdx.x;               // 32768 = B*T
  int b = bi >> 9, t = bi & 511;
  const float* src = x + ((size_t)b * TT + t) * 1024;
  u16* dst = xb + ((size_t)t * BB + b) * 1024;
  int i = threadIdx.x * 4;
  float4 v = *(const float4*)(src + i);
  u16x4 o; o[0] = f2bf(v.x); o[1] = f2bf(v.y); o[2] = f2bf(v.z); o[3] = f2bf(v.w);
  *(u16x4*)(dst + i) = o;
}

// ------------------------------------------------------------------- sync ops
__device__ inline void poll1(unsigned* p) {
  while (__hip_atomic_load(p, __ATOMIC_RELAXED, __HIP_MEMORY_SCOPE_SYSTEM) == 0u)
    __builtin_amdgcn_s_sleep(1);
}

// ------------------------------------------- pipelined A-fragment load + MFMA
// load_a8: issue all 8 16B fragments (this wave's 16 rows x 256-K slice) so
// they are simultaneously outstanding -> one L3/system latency, not eight.
template<bool COHA>
__device__ inline void load_a8(const u16* Abase, size_t aoff, bf16x8* a) {
  const u16* ap = Abase + aoff;
  #pragma unroll
  for (int ks = 0; ks < 8; ++ks) {
    if constexpr (COHA) {
      u64 lo = __hip_atomic_load((u64*)(ap + ks * 32),     __ATOMIC_RELAXED, __HIP_MEMORY_SCOPE_SYSTEM);
      u64 hi = __hip_atomic_load((u64*)(ap + ks * 32 + 4), __ATOMIC_RELAXED, __HIP_MEMORY_SCOPE_SYSTEM);
      union { u64 q2[2]; bf16x8 v; } un; un.q2[0] = lo; un.q2[1] = hi;
      a[ks] = un.v;
    } else {
      a[ks] = __builtin_bit_cast(bf16x8, *(const u16x8*)(ap + ks * 32));
    }
  }
}

__device__ inline void fma8(const bf16x8* a, const u16* bp,
                            int gbase, int n15, f32x4& acc0, f32x4& acc1) {
  #pragma unroll
  for (int ks = 0; ks < 8; ++ks) {
    int g = (gbase + 4 * ks) ^ n15;          // XOR-16B swizzled group
    bf16x8 b0 = __builtin_bit_cast(bf16x8, *(const u16x8*)(bp + g * 8));
    bf16x8 b1 = __builtin_bit_cast(bf16x8, *(const u16x8*)(bp + 16 * 1024 + g * 8));
    acc0 = __builtin_amdgcn_mfma_f32_16x16x32_bf16(a[ks], b0, acc0, 0, 0, 0);
    acc1 = __builtin_amdgcn_mfma_f32_16x16x32_bf16(a[ks], b1, acc1, 0, 0, 0);
  }
}

// ------------------------------------------------------------- main persistent
template<bool COH>
__global__ void __launch_bounds__(1024, 1)
rnn_seq(const float* __restrict__ x, const float* __restrict__ b0v,
        const float* __restrict__ b1v, float* __restrict__ out,
        unsigned* __restrict__ flags, const u16* __restrict__ W0t,
        const u16* __restrict__ W1t, u16* __restrict__ h0r,
        u16* __restrict__ h1r, u16* __restrict__ ur,
        const u16* __restrict__ xb, int use_xb) {
  constexpr int RMASK = COH ? 15 : 511;
  constexpr int UMASK = COH ? 31 : 511;
  constexpr int RING = 16, URING = 32;
  extern __shared__ u16 lds[];
  unsigned* fl_h0 = flags;
  unsigned* fl_h1 = flags + 512 * 32;
  unsigned* fl_u  = flags + 2 * 512 * 32;

  int wg = blockIdx.x, tid = threadIdx.x;
  int grp = wg >> 5, j = wg & 31;        // 0=L0, 1=L1, 2=U
  int n0 = j * 32;
  int lane = tid & 63, wave = tid >> 6;  // 16 waves
  int rb = wave & 3, ksl = wave >> 2;    // row-block, K-slice
  int n15 = lane & 15, q = lane >> 4;
  int r0 = rb * 16;

  // LDS regions
  u16*   wlds = lds;
  float* scr  = (float*)((char*)lds + ((grp == 1) ? 131072 : 65536));
  u16*   hch  = (u16*)((char*)scr + 24576);
  u32*   uc   = (u32*)((char*)hch + 4096);   // G0 only

  // ---- persistent LDS weights, XOR-16B swizzle, [half][n][k]
  {
    const u16* Wt = (grp == 1) ? W1t : W0t;
    int nh = (grp == 1) ? 2 : 1;
    for (int h = 0; h < nh; ++h) {
      int kb = (grp == 1) ? h * 1024 : (grp == 2 ? 1024 : 0);
      for (int idx = tid; idx < 32 * 128; idx += 1024) {
        int n = idx >> 7, g = idx & 127;
        u16x8 v = *(const u16x8*)(Wt + (size_t)(n0 + n) * 2048 + kb + g * 8);
        *(u16x8*)(wlds + h * 32768 + n * 1024 + ((g ^ (n & 15)) * 8)) = v;
      }
    }
  }
  __syncthreads();

  const size_t aoff = (size_t)(r0 + n15) * 1024 + ksl * 256 + q * 8;
  const int gbase = 32 * ksl + q;
  const u16* bp0 = wlds + n15 * 1024;            // weights half 0
  const u16* bp1 = wlds + 32768 + n15 * 1024;    // weights half 1 (G1)

  // biases hoisted (per-lane constants)
  float bia = 0.f, bib = 0.f;
  if (grp == 1) { bia = b1v[n0 + n15]; bib = b1v[n0 + n15 + 16]; }
  if (grp == 2) { bia = b0v[n0 + n15]; bib = b0v[n0 + n15 + 16]; }

  // split-K reduce helpers ------------------------------------------------
  auto scr_write = [&](const f32x4& a0, const f32x4& a1) {   // waves ksl>0
    int base = ((rb * 3 + ksl - 1) * 2) * 256 + (q * 4) * 16 + n15;
    #pragma unroll
    for (int i = 0; i < 4; ++i) scr[base + i * 16] = a0[i];
    #pragma unroll
    for (int i = 0; i < 4; ++i) scr[base + 256 + i * 16] = a1[i];
  };
  auto scr_sum = [&](f32x4& a0, f32x4& a1) {                 // waves ksl==0
    #pragma unroll
    for (int s = 0; s < 3; ++s) {
      int base = ((rb * 3 + s) * 2) * 256 + (q * 4) * 16 + n15;
      #pragma unroll
      for (int i = 0; i < 4; ++i) a0[i] += scr[base + i * 16];
      #pragma unroll
      for (int i = 0; i < 4; ++i) a1[i] += scr[base + 256 + i * 16];
    }
  };
  // coalesced ring store: thread -> 4 B
  const int sb  = tid >> 4;              // 0..63 (batch row)
  const int scc = (tid & 15) * 2;        // col pair
  auto ring_store = [&](u16* slab) {
    u32 v = ((u32*)hch)[tid];
    __hip_atomic_store((u32*)(slab + sb * 1024 + n0 + scc), v,
                       __ATOMIC_RELAXED, __HIP_MEMORY_SCOPE_SYSTEM);
  };

  const size_t FIN = (size_t)BB * TT * 1024;

  if (grp == 0) {            // ---- G0: h0(t) = tanh(Wh0*h0(t-1) + U(t))
    for (int t = 0; t < TT; ++t) {
      if (tid < 32)      { if (t > 0)            poll1(&fl_h0[(t - 1) * 32 + tid]); }
      else if (tid < 64) {                       poll1(&fl_u [t * 32 + (tid - 32)]); }
      else if (tid < 96) { if (COH && t >= RING) poll1(&fl_h1[(t - RING) * 32 + (tid - 64)]); }
      __syncthreads();                                   // B1
      bf16x8 a[8];
      if (t > 0) load_a8<COH>(h0r + (size_t)((t - 1) & RMASK) * SLOT, aoff, a);
      {  // ucache fill: one coalesced 4-B load per thread (issued in the
         // same window as the A-slab loads)
        const u16* us = ur + (size_t)(t & UMASK) * SLOT;
        const u32* up = (const u32*)(us + sb * 1024 + n0 + scc);
        u32 v = COH ? __hip_atomic_load((u32*)up, __ATOMIC_RELAXED, __HIP_MEMORY_SCOPE_SYSTEM)
                    : *up;
        uc[tid] = v;
      }
      f32x4 acc0 = {0.f, 0.f, 0.f, 0.f}, acc1 = acc0;
      if (t > 0) fma8(a, bp0, gbase, n15, acc0, acc1);
      if (ksl > 0) scr_write(acc0, acc1);
      __syncthreads();                                   // B2
      if (ksl == 0) {
        scr_sum(acc0, acc1);
        #pragma unroll
        for (int i = 0; i < 4; ++i) {
          int b = r0 + q * 4 + i;
          float u0 = bf2f(((u16*)uc)[b * 32 + n15]);
          float u1 = bf2f(((u16*)uc)[b * 32 + n15 + 16]);
          hch[b * 32 + n15]      = f2bf(fast_tanh(acc0[i] + u0));
          hch[b * 32 + n15 + 16] = f2bf(fast_tanh(acc1[i] + u1));
        }
      }
      __syncthreads();                                   // B3
      ring_store(h0r + (size_t)(t & RMASK) * SLOT);
      __syncthreads();                                   // B4: vmcnt(0) drain
      if (tid == 0)
        __hip_atomic_store(&fl_h0[t * 32 + j], 1u, __ATOMIC_RELAXED, __HIP_MEMORY_SCOPE_SYSTEM);
      if (t == TT - 1) {   // final state (non-critical, after flag)
        u32 v = ((u32*)hch)[tid];
        float2 o; o.x = bf2f((u16)(v & 0xffff)); o.y = bf2f((u16)(v >> 16));
        *(float2*)&out[FIN + (size_t)sb * 2048 + n0 + scc] = o;
      }
    }
  } else if (grp == 1) {     // ---- G1: h1(t) = tanh(W1*[h1(t-1); h0(t)] + b1)
    for (int t = 0; t < TT; ++t) {
      // h1(t-1) half FIRST: flags are old news, loads+MFMAs hide in the
      // window where h0(t) is not yet ready.
      if (tid < 32 && t > 0) poll1(&fl_h1[(t - 1) * 32 + tid]);
      __syncthreads();                                   // B1
      f32x4 acc0 = {0.f, 0.f, 0.f, 0.f}, acc1 = acc0;
      if (t > 0) {
        bf16x8 a1[8];
        load_a8<COH>(h1r + (size_t)((t - 1) & RMASK) * SLOT, aoff, a1);
        fma8(a1, bp0, gbase, n15, acc0, acc1);
      }
      // h0(t): the fresh dependency -> one batched load latency
      if (tid < 32) poll1(&fl_h0[t * 32 + tid]);
      __syncthreads();                                   // B1b
      {
        bf16x8 a0[8];
        load_a8<COH>(h0r + (size_t)(t & RMASK) * SLOT, aoff, a0);
        fma8(a0, bp1, gbase, n15, acc0, acc1);
      }
      if (ksl > 0) scr_write(acc0, acc1);
      __syncthreads();                                   // B2
      if (ksl == 0) {
        scr_sum(acc0, acc1);
        #pragma unroll
        for (int i = 0; i < 4; ++i) {
          int b = r0 + q * 4 + i;
          hch[b * 32 + n15]      = f2bf(fast_tanh(acc0[i] + bia));
          hch[b * 32 + n15 + 16] = f2bf(fast_tanh(acc1[i] + bib));
        }
      }
      __syncthreads();                                   // B3
      ring_store(h1r + (size_t)(t & RMASK) * SLOT);
      __syncthreads();                                   // B4
      if (tid == 0)
        __hip_atomic_store(&fl_h1[t * 32 + j], 1u, __ATOMIC_RELAXED, __HIP_MEMORY_SCOPE_SYSTEM);
      {  // out stores AFTER flag (off the critical drain), coalesced 8 B
        u32 v = ((u32*)hch)[tid];
        float2 o; o.x = bf2f((u16)(v & 0xffff)); o.y = bf2f((u16)(v >> 16));
        __builtin_nontemporal_store(o.x, &out[((size_t)sb * TT + t) * 1024 + n0 + scc]);
        __builtin_nontemporal_store(o.y, &out[((size_t)sb * TT + t) * 1024 + n0 + scc + 1]);
        if (t == TT - 1)
          *(float2*)&out[FIN + (size_t)sb * 2048 + 1024 + n0 + scc] = o;
      }
    }
  } else {                   // ---- G2: U(t) = Wx*x(t) + b0 (free-runs)
    for (int t = 0; t < TT; ++t) {
      if (COH && t >= URING) {
        if (tid < 32) poll1(&fl_h0[(t - URING) * 32 + tid]);
      }
      __syncthreads();                                   // B1
      f32x4 acc0 = {0.f, 0.f, 0.f, 0.f}, acc1 = acc0;
      bf16x8 a[8];
      if (use_xb) {
        load_a8<false>(xb + (size_t)t * SLOT, aoff, a);
      } else {
        const float* Ap = x + ((size_t)(r0 + n15) * TT + t) * 1024 + ksl * 256 + q * 8;
        float4 f[16];
        #pragma unroll
        for (int ks = 0; ks < 8; ++ks) {
          f[2 * ks]     = *(const float4*)(Ap + ks * 32);
          f[2 * ks + 1] = *(const float4*)(Ap + ks * 32 + 4);
        }
        #pragma unroll
        for (int ks = 0; ks < 8; ++ks) {
          bf16x8 tv;
          tv[0] = (__bf16)f[2*ks].x;   tv[1] = (__bf16)f[2*ks].y;
          tv[2] = (__bf16)f[2*ks].z;   tv[3] = (__bf16)f[2*ks].w;
          tv[4] = (__bf16)f[2*ks+1].x; tv[5] = (__bf16)f[2*ks+1].y;
          tv[6] = (__bf16)f[2*ks+1].z; tv[7] = (__bf16)f[2*ks+1].w;
          a[ks] = tv;
        }
      }
      fma8(a, bp0, gbase, n15, acc0, acc1);
      if (ksl > 0) scr_write(acc0, acc1);
      __syncthreads();                                   // B2
      if (ksl == 0) {
        scr_sum(acc0, acc1);
        #pragma unroll
        for (int i = 0; i < 4; ++i) {
          int b = r0 + q * 4 + i;
          hch[b * 32 + n15]      = f2bf(acc0[i] + bia);
          hch[b * 32 + n15 + 16] = f2bf(acc1[i] + bib);
        }
      }
      __syncthreads();                                   // B3
      ring_store(ur + (size_t)(t & UMASK) * SLOT);
      __syncthreads();                                   // B4
      if (tid == 0)
        __hip_atomic_store(&fl_u[t * 32 + j], 1u, __ATOMIC_RELAXED, __HIP_MEMORY_SCOPE_SYSTEM);
    }
  }
}

// ------------------------------------------------------------------ host side
extern "C" void kernel_launch(void* const* d_in, const int* in_sizes, int n_in,
                              void* d_out, int out_size, void* d_ws, size_t ws_size,
                              hipStream_t stream) {
  const float* x  = (const float*)d_in[0];
  const float* W0 = (const float*)d_in[1];
  const float* b0 = (const float*)d_in[2];
  const float* W1 = (const float*)d_in[3];
  const float* b1 = (const float*)d_in[4];
  float* out = (float*)d_out;
  unsigned char* ws = (unsigned char*)d_ws;

  const size_t WS_PLAIN = OFF_R + 4ull * 512 * SLAB_B;            // ~277 MB
  bool plain = ws_size >= WS_PLAIN;
  size_t nslot  = plain ? 512 : 16;
  size_t nuslot = plain ? 512 : 32;
  size_t o_h0 = OFF_R;
  size_t o_h1 = o_h0 + nslot  * SLAB_B;
  size_t o_u  = o_h1 + nslot  * SLAB_B;
  size_t o_xb = o_u  + nuslot * SLAB_B;
  int use_xb = (plain || ws_size >= o_xb + (size_t)TT * SLAB_B) ? 1 : 0;

  unsigned* flags = (unsigned*)ws;
  const u16* W0t = (const u16*)(ws + OFF_W0T);
  const u16* W1t = (const u16*)(ws + OFF_W1T);
  u16* h0r = (u16*)(ws + o_h0);
  u16* h1r = (u16*)(ws + o_h1);
  u16* ur  = (u16*)(ws + o_u);
  u16* xb  = (u16*)(ws + o_xb);

  zero_flags<<<192, 256, 0, stream>>>(flags);
  transpose_w<<<1024, 256, 0, stream>>>(W0, W1, (u16*)(ws + OFF_W0T));
  if (use_xb) xconv<<<32768, 256, 0, stream>>>(x, xb);

  (void)hipFuncSetAttribute((const void*)rnn_seq<false>,
                            hipFuncAttributeMaxDynamicSharedMemorySize, LDS_REQ);
  (void)hipFuncSetAttribute((const void*)rnn_seq<true>,
                            hipFuncAttributeMaxDynamicSharedMemorySize, LDS_REQ);

  void* args[12];
  args[0]  = (void*)&x;    args[1]  = (void*)&b0;   args[2]  = (void*)&b1;
  args[3]  = (void*)&out;  args[4]  = (void*)&flags;
  args[5]  = (void*)&W0t;  args[6]  = (void*)&W1t;
  args[7]  = (void*)&h0r;  args[8]  = (void*)&h1r;  args[9]  = (void*)&ur;
  args[10] = (void*)&xb;   args[11] = (void*)&use_xb;
  hipLaunchCooperativeKernel(plain ? (void*)rnn_seq<false> : (void*)rnn_seq<true>,
                             dim3(96), dim3(1024), args, LDS_REQ, stream);
}

// Round 3
// 4872.734 us; speedup vs baseline: 1.0034x; 1.0034x over previous
//
#include <hip/hip_runtime.h>
#include <cmath>

// ---------------------------------------------------------------------------
// 2-layer tanh RNN, B=64, T=512, D=H0=H1=1024. Persistent cooperative kernel.
// Round-7: shorten the per-step serial chains, sync protocol unchanged
// (block-wide polls -> B1 -> work -> B2 -> epilogue -> store -> B4 drain ->
// flag; verified rounds 2-4/6).
//  * G1 half-split: 16 waves = 4 row-blocks x {h0-half, h1-half} x 2 K-slices.
//    The h0(t) and h1(t-1) GEMM halves run in DIFFERENT waves concurrently,
//    so G1's h1->h1 self-chain has ONE slab-load+fma phase, not two, and
//    barrier B1b is gone. Split-K reduce via scr (4 slices) unchanged.
//  * G0/G2 all-thread epilogue: every wave writes its partial to a 32KB scr;
//    after B2 each thread sums its own 2 output columns (col_sum), adds its
//    own U word / bias in-register, tanh, stores pv directly. Removes the
//    hch+uc LDS bounces and barrier B3 from the G0/G2 chains.
// Groups (32 WGs each, cols split 32/WG):
//   G0: h0(t) = tanh(Wh0*h0(t-1) + U(t))                [K=1024]
//   G1: h1(t) = tanh(W1*[h1(t-1); h0(t)] + b1)          [K=2048]
//   G2: U(t)  = Wx*x(t) + b0   (free-runs ahead)        [K=1024]
// Sync: relaxed SYSTEM flags/data (write-through, no cache maintenance);
// producer order via __syncthreads' vmcnt(0) drain before the flag store.
// ---------------------------------------------------------------------------

typedef unsigned short u16;
typedef unsigned int   u32;
typedef unsigned long long u64;
typedef __bf16 bf16x8 __attribute__((ext_vector_type(8)));
typedef u16    u16x8  __attribute__((ext_vector_type(8)));
typedef u16    u16x4  __attribute__((ext_vector_type(4)));
typedef float  f32x4  __attribute__((ext_vector_type(4)));

constexpr int BB = 64;
constexpr int TT = 512;
constexpr size_t SLOT   = (size_t)64 * 1024;   // elements per [64][1024] slab
constexpr size_t SLAB_B = SLOT * 2;            // 128 KB bf16 slab

constexpr size_t OFF_W0T = 262144;             // flags in [0, 256K)
constexpr size_t OFF_W1T = OFF_W0T + (size_t)1024 * 2048 * 2;
constexpr size_t OFF_R   = OFF_W1T + (size_t)1024 * 2048 * 2;

// LDS budget (dynamic): G1: 128K weights + 24K scr + 4K hch = 156K
//                       G0/G2: 64K weights + 32K scr        =  96K
constexpr int LDS_REQ = 159744;

__device__ inline u16 f2bf(float f) { return __builtin_bit_cast(u16, (__bf16)f); }
__device__ inline float bf2f(u16 v) { return (float)__builtin_bit_cast(__bf16, v); }
__device__ inline float fast_tanh(float x) {
  x = fminf(15.f, fmaxf(-15.f, x));
  float e = __expf(2.f * x);
  return (e - 1.f) * __builtin_amdgcn_rcpf(e + 1.f);
}

// ---------------------------------------------------------------- prep kernels
__global__ void zero_flags(unsigned* f) {
  int i = blockIdx.x * 256 + threadIdx.x;
  if (i < 3 * 512 * 32) f[i] = 0;
}

__global__ void transpose_w(const float* __restrict__ W0,
                            const float* __restrict__ W1,
                            u16* __restrict__ wt_base) {
  __shared__ float tile[64][65];
  int bi  = blockIdx.x;
  int mat = bi >> 9;
  int t   = bi & 511;
  int tk = t & 31, tn = t >> 5;
  const float* W = mat ? W1 : W0;
  u16* Wt = wt_base + (size_t)mat * 1024 * 2048;
  int K0 = tk * 64, N0 = tn * 64;
  int tid = threadIdx.x;
  {
    int c4 = (tid & 15) * 4;
    int r  = tid >> 4;
    for (int i = 0; i < 4; ++i) {
      int kl = r + i * 16;
      float4 v = *(const float4*)(W + (size_t)(K0 + kl) * 1024 + N0 + c4);
      tile[kl][c4 + 0] = v.x; tile[kl][c4 + 1] = v.y;
      tile[kl][c4 + 2] = v.z; tile[kl][c4 + 3] = v.w;
    }
  }
  __syncthreads();
  {
    int nl = tid >> 3;
    int kc = (tid & 7) * 8;
    for (int pass = 0; pass < 2; ++pass) {
      int n = nl + pass * 32;
      u16x8 o;
      #pragma unroll
      for (int z = 0; z < 8; ++z) o[z] = f2bf(tile[kc + z][n]);
      *(u16x8*)(Wt + (size_t)(N0 + n) * 2048 + K0 + kc) = o;
    }
  }
}

__global__ void xconv(const float* __restrict__ x, u16* __restrict__ xb) {
  int bi = blockIdx.x;               // 32768 = B*T
  int b = bi >> 9, t = bi & 511;
  const float* src = x + ((size_t)b * TT + t) * 1024;
  u16* dst = xb + ((size_t)t * BB + b) * 1024;
  int i = threadIdx.x * 4;
  float4 v = *(const float4*)(src + i);
  u16x4 o; o[0] = f2bf(v.x); o[1] = f2bf(v.y); o[2] = f2bf(v.z); o[3] = f2bf(v.w);
  *(u16x4*)(dst + i) = o;
}

// ------------------------------------------------------------------- sync ops
__device__ inline void poll1(unsigned* p) {
  while (__hip_atomic_load(p, __ATOMIC_RELAXED, __HIP_MEMORY_SCOPE_SYSTEM) == 0u)
    __builtin_amdgcn_s_sleep(1);
}

// ------------------------------------------- pipelined A-fragment load + MFMA
template<bool COHA>
__device__ inline void load_a8(const u16* Abase, size_t aoff, bf16x8* a) {
  const u16* ap = Abase + aoff;
  #pragma unroll
  for (int ks = 0; ks < 8; ++ks) {
    if constexpr (COHA) {
      u64 lo = __hip_atomic_load((u64*)(ap + ks * 32),     __ATOMIC_RELAXED, __HIP_MEMORY_SCOPE_SYSTEM);
      u64 hi = __hip_atomic_load((u64*)(ap + ks * 32 + 4), __ATOMIC_RELAXED, __HIP_MEMORY_SCOPE_SYSTEM);
      union { u64 q2[2]; bf16x8 v; } un; un.q2[0] = lo; un.q2[1] = hi;
      a[ks] = un.v;
    } else {
      a[ks] = __builtin_bit_cast(bf16x8, *(const u16x8*)(ap + ks * 32));
    }
  }
}

__device__ inline void fma8(const bf16x8* a, const u16* bp,
                            int gbase, int n15, f32x4& acc0, f32x4& acc1) {
  #pragma unroll
  for (int ks = 0; ks < 8; ++ks) {
    int g = (gbase + 4 * ks) ^ n15;          // XOR-16B swizzled group
    bf16x8 b0 = __builtin_bit_cast(bf16x8, *(const u16x8*)(bp + g * 8));
    bf16x8 b1 = __builtin_bit_cast(bf16x8, *(const u16x8*)(bp + 16 * 1024 + g * 8));
    acc0 = __builtin_amdgcn_mfma_f32_16x16x32_bf16(a[ks], b0, acc0, 0, 0, 0);
    acc1 = __builtin_amdgcn_mfma_f32_16x16x32_bf16(a[ks], b1, acc1, 0, 0, 0);
  }
}

// ------------------------------------------------------------- main persistent
template<bool COH>
__global__ void __launch_bounds__(1024, 1)
rnn_seq(const float* __restrict__ x, const float* __restrict__ b0v,
        const float* __restrict__ b1v, float* __restrict__ out,
        unsigned* __restrict__ flags, const u16* __restrict__ W0t,
        const u16* __restrict__ W1t, u16* __restrict__ h0r,
        u16* __restrict__ h1r, u16* __restrict__ ur,
        const u16* __restrict__ xb, int use_xb) {
  constexpr int RMASK = COH ? 15 : 511;
  constexpr int UMASK = COH ? 31 : 511;
  constexpr int RING = 16, URING = 32;
  extern __shared__ u16 lds[];
  unsigned* fl_h0 = flags;
  unsigned* fl_h1 = flags + 512 * 32;
  unsigned* fl_u  = flags + 2 * 512 * 32;

  int wg = blockIdx.x, tid = threadIdx.x;
  int grp = wg >> 5, j = wg & 31;        // 0=L0, 1=L1, 2=U
  int n0 = j * 32;
  int lane = tid & 63, wave = tid >> 6;  // 16 waves
  int rb = wave & 3;                     // row-block
  int ksl = wave >> 2;                   // G0/G2: K-slice; G1: slice id
  int n15 = lane & 15, q = lane >> 4;
  int r0 = rb * 16;

  // LDS regions
  u16*   wlds = lds;
  float* scr  = (float*)((char*)lds + ((grp == 1) ? 131072 : 65536));
  u16*   hch  = (u16*)((char*)scr + 24576);   // G1 only

  // ---- persistent LDS weights, XOR-16B swizzle, [half][n][k]
  {
    const u16* Wt = (grp == 1) ? W1t : W0t;
    int nh = (grp == 1) ? 2 : 1;
    for (int h = 0; h < nh; ++h) {
      int kb = (grp == 1) ? h * 1024 : (grp == 2 ? 1024 : 0);
      for (int idx = tid; idx < 32 * 128; idx += 1024) {
        int n = idx >> 7, g = idx & 127;
        u16x8 v = *(const u16x8*)(Wt + (size_t)(n0 + n) * 2048 + kb + g * 8);
        *(u16x8*)(wlds + h * 32768 + n * 1024 + ((g ^ (n & 15)) * 8)) = v;
      }
    }
  }
  __syncthreads();

  const size_t aoff = (size_t)(r0 + n15) * 1024 + ksl * 256 + q * 8;  // G0/G2
  const int gbase = 32 * ksl + q;                                     // G0/G2
  const u16* bp0 = wlds + n15 * 1024;            // weights half 0
  const u16* bp1 = wlds + 32768 + n15 * 1024;    // weights half 1 (G1)

  // G1 half-split geometry: slice = wave>>2 (0..3); half 0 = h0(t) (bp1),
  // half 1 = h1(t-1) (bp0); each half split into 2 K-slices of 512.
  const int slice = wave >> 2;
  const int half  = slice >> 1;
  const int ksl2  = slice & 1;
  const size_t aoffS = (size_t)(r0 + n15) * 1024 + ksl2 * 512 + q * 8;
  const int gbaseS = 64 * ksl2 + q;
  const u16* bpH = half ? bp0 : bp1;

  // per-thread output-slot mapping (1 u32 = 2 cols per thread)
  const int sb  = tid >> 4;              // 0..63 (batch row)
  const int scc = (tid & 15) * 2;        // col pair base
  const int rbT = sb >> 4, rr = sb & 15;

  // biases
  float bia = 0.f, bib = 0.f;            // G1 (n15 mapping, slice0 epilogue)
  if (grp == 1) { bia = b1v[n0 + n15]; bib = b1v[n0 + n15 + 16]; }
  float2 b2x = {0.f, 0.f};               // G2 (per-thread col mapping)
  if (grp == 2) b2x = *(const float2*)&b0v[n0 + scc];

  // ---- G1 split-K helpers (3 slices write, slice0 sums -> hch)
  auto scr_write = [&](int s, const f32x4& a0, const f32x4& a1) {
    int base = ((rb * 3 + s - 1) * 2) * 256 + (q * 4) * 16 + n15;
    #pragma unroll
    for (int i = 0; i < 4; ++i) scr[base + i * 16] = a0[i];
    #pragma unroll
    for (int i = 0; i < 4; ++i) scr[base + 256 + i * 16] = a1[i];
  };
  auto scr_sum = [&](f32x4& a0, f32x4& a1) {
    #pragma unroll
    for (int s = 0; s < 3; ++s) {
      int base = ((rb * 3 + s) * 2) * 256 + (q * 4) * 16 + n15;
      #pragma unroll
      for (int i = 0; i < 4; ++i) a0[i] += scr[base + i * 16];
      #pragma unroll
      for (int i = 0; i < 4; ++i) a1[i] += scr[base + 256 + i * 16];
    }
  };

  // ---- G0/G2 all-wave split-K: every wave writes its slice; every thread
  // then sums its own 2 output columns. 32KB scr: [rb][ksl][rr][tile*256+c]
  auto scr_put = [&](const f32x4& a0, const f32x4& a1) {
    int base = rb * 2048 + ksl * 512 + (q * 4) * 16 + n15;
    #pragma unroll
    for (int i = 0; i < 4; ++i) scr[base + i * 16] = a0[i];
    #pragma unroll
    for (int i = 0; i < 4; ++i) scr[base + 256 + i * 16] = a1[i];
  };
  auto col_sum = [&](int c2) -> float {
    int base = rbT * 2048 + (c2 >> 4) * 256 + rr * 16 + (c2 & 15);
    return (scr[base] + scr[base + 512]) + (scr[base + 1024] + scr[base + 1536]);
  };

  const size_t FIN = (size_t)BB * TT * 1024;

  if (grp == 0) {            // ---- G0: h0(t) = tanh(Wh0*h0(t-1) + U(t))
    for (int t = 0; t < TT; ++t) {
      if (tid < 32)      { if (t > 0)            poll1(&fl_h0[(t - 1) * 32 + tid]); }
      else if (tid < 64) {                       poll1(&fl_u [t * 32 + (tid - 32)]); }
      else if (tid < 96) { if (COH && t >= RING) poll1(&fl_h1[(t - RING) * 32 + (tid - 64)]); }
      __syncthreads();                                   // B1
      bf16x8 a[8];
      if (t > 0) load_a8<COH>(h0r + (size_t)((t - 1) & RMASK) * SLOT, aoff, a);
      u32 uval;
      {  // own U word, coalesced 4 B/thread, issued in the load window
        const u32* up = (const u32*)(ur + (size_t)(t & UMASK) * SLOT + sb * 1024 + n0 + scc);
        uval = COH ? __hip_atomic_load((u32*)up, __ATOMIC_RELAXED, __HIP_MEMORY_SCOPE_SYSTEM)
                   : *up;
      }
      f32x4 acc0 = {0.f, 0.f, 0.f, 0.f}, acc1 = acc0;
      if (t > 0) fma8(a, bp0, gbase, n15, acc0, acc1);
      scr_put(acc0, acc1);
      __syncthreads();                                   // B2
      float v0 = fast_tanh(col_sum(scc)     + bf2f((u16)(uval & 0xffffu)));
      float v1 = fast_tanh(col_sum(scc + 1) + bf2f((u16)(uval >> 16)));
      u32 pv = (u32)f2bf(v0) | ((u32)f2bf(v1) << 16);
      __hip_atomic_store((u32*)(h0r + (size_t)(t & RMASK) * SLOT + sb * 1024 + n0 + scc),
                         pv, __ATOMIC_RELAXED, __HIP_MEMORY_SCOPE_SYSTEM);
      __syncthreads();                                   // B4: vmcnt(0) drain
      if (tid == 0)
        __hip_atomic_store(&fl_h0[t * 32 + j], 1u, __ATOMIC_RELAXED, __HIP_MEMORY_SCOPE_SYSTEM);
      if (t == TT - 1) {   // final state (non-critical, after flag)
        float2 o; o.x = v0; o.y = v1;
        *(float2*)&out[FIN + (size_t)sb * 2048 + n0 + scc] = o;
      }
    }
  } else if (grp == 1) {     // ---- G1: h1(t) = tanh(W1*[h1(t-1); h0(t)] + b1)
    for (int t = 0; t < TT; ++t) {
      if (tid < 32)      { poll1(&fl_h0[t * 32 + tid]); }
      else if (tid < 64) { if (t > 0) poll1(&fl_h1[(t - 1) * 32 + (tid - 32)]); }
      __syncthreads();                                   // B1
      f32x4 acc0 = {0.f, 0.f, 0.f, 0.f}, acc1 = acc0;
      if (half == 0) {                 // h0(t) half, weights half 1
        bf16x8 a[16];
        const u16* s0 = h0r + (size_t)(t & RMASK) * SLOT;
        load_a8<COH>(s0, aoffS, a);
        load_a8<COH>(s0, aoffS + 256, a + 8);
        fma8(a,     bpH, gbaseS,      n15, acc0, acc1);
        fma8(a + 8, bpH, gbaseS + 32, n15, acc0, acc1);
      } else if (t > 0) {              // h1(t-1) half, weights half 0
        bf16x8 a[16];
        const u16* s1 = h1r + (size_t)((t - 1) & RMASK) * SLOT;
        load_a8<COH>(s1, aoffS, a);
        load_a8<COH>(s1, aoffS + 256, a + 8);
        fma8(a,     bpH, gbaseS,      n15, acc0, acc1);
        fma8(a + 8, bpH, gbaseS + 32, n15, acc0, acc1);
      }
      if (slice > 0) scr_write(slice, acc0, acc1);
      __syncthreads();                                   // B2
      if (slice == 0) {
        scr_sum(acc0, acc1);
        #pragma unroll
        for (int i = 0; i < 4; ++i) {
          int b = r0 + q * 4 + i;
          hch[b * 32 + n15]      = f2bf(fast_tanh(acc0[i] + bia));
          hch[b * 32 + n15 + 16] = f2bf(fast_tanh(acc1[i] + bib));
        }
      }
      __syncthreads();                                   // B3
      u32 pv = ((u32*)hch)[tid];
      __hip_atomic_store((u32*)(h1r + (size_t)(t & RMASK) * SLOT + sb * 1024 + n0 + scc),
                         pv, __ATOMIC_RELAXED, __HIP_MEMORY_SCOPE_SYSTEM);
      __syncthreads();                                   // B4
      if (tid == 0)
        __hip_atomic_store(&fl_h1[t * 32 + j], 1u, __ATOMIC_RELAXED, __HIP_MEMORY_SCOPE_SYSTEM);
      {  // out stores AFTER flag (off the critical drain), coalesced 8 B
        float2 o; o.x = bf2f((u16)(pv & 0xffffu)); o.y = bf2f((u16)(pv >> 16));
        __builtin_nontemporal_store(o.x, &out[((size_t)sb * TT + t) * 1024 + n0 + scc]);
        __builtin_nontemporal_store(o.y, &out[((size_t)sb * TT + t) * 1024 + n0 + scc + 1]);
        if (t == TT - 1)
          *(float2*)&out[FIN + (size_t)sb * 2048 + 1024 + n0 + scc] = o;
      }
    }
  } else {                   // ---- G2: U(t) = Wx*x(t) + b0 (free-runs)
    for (int t = 0; t < TT; ++t) {
      if (COH && t >= URING) {
        if (tid < 32) poll1(&fl_h0[(t - URING) * 32 + tid]);
      }
      __syncthreads();                                   // B1
      bf16x8 a[8];
      if (use_xb) {
        load_a8<false>(xb + (size_t)t * SLOT, aoff, a);
      } else {
        const float* Ap = x + ((size_t)(r0 + n15) * TT + t) * 1024 + ksl * 256 + q * 8;
        float4 f[16];
        #pragma unroll
        for (int ks = 0; ks < 8; ++ks) {
          f[2 * ks]     = *(const float4*)(Ap + ks * 32);
          f[2 * ks + 1] = *(const float4*)(Ap + ks * 32 + 4);
        }
        #pragma unroll
        for (int ks = 0; ks < 8; ++ks) {
          bf16x8 tv;
          tv[0] = (__bf16)f[2*ks].x;   tv[1] = (__bf16)f[2*ks].y;
          tv[2] = (__bf16)f[2*ks].z;   tv[3] = (__bf16)f[2*ks].w;
          tv[4] = (__bf16)f[2*ks+1].x; tv[5] = (__bf16)f[2*ks+1].y;
          tv[6] = (__bf16)f[2*ks+1].z; tv[7] = (__bf16)f[2*ks+1].w;
          a[ks] = tv;
        }
      }
      f32x4 acc0 = {0.f, 0.f, 0.f, 0.f}, acc1 = acc0;
      fma8(a, bp0, gbase, n15, acc0, acc1);
      scr_put(acc0, acc1);
      __syncthreads();                                   // B2
      float v0 = col_sum(scc)     + b2x.x;
      float v1 = col_sum(scc + 1) + b2x.y;
      u32 pv = (u32)f2bf(v0) | ((u32)f2bf(v1) << 16);
      __hip_atomic_store((u32*)(ur + (size_t)(t & UMASK) * SLOT + sb * 1024 + n0 + scc),
                         pv, __ATOMIC_RELAXED, __HIP_MEMORY_SCOPE_SYSTEM);
      __syncthreads();                                   // B4
      if (tid == 0)
        __hip_atomic_store(&fl_u[t * 32 + j], 1u, __ATOMIC_RELAXED, __HIP_MEMORY_SCOPE_SYSTEM);
    }
  }
}

// ------------------------------------------------------------------ host side
extern "C" void kernel_launch(void* const* d_in, const int* in_sizes, int n_in,
                              void* d_out, int out_size, void* d_ws, size_t ws_size,
                              hipStream_t stream) {
  const float* x  = (const float*)d_in[0];
  const float* W0 = (const float*)d_in[1];
  const float* b0 = (const float*)d_in[2];
  const float* W1 = (const float*)d_in[3];
  const float* b1 = (const float*)d_in[4];
  float* out = (float*)d_out;
  unsigned char* ws = (unsigned char*)d_ws;

  const size_t WS_PLAIN = OFF_R + 4ull * 512 * SLAB_B;            // ~277 MB
  bool plain = ws_size >= WS_PLAIN;
  size_t nslot  = plain ? 512 : 16;
  size_t nuslot = plain ? 512 : 32;
  size_t o_h0 = OFF_R;
  size_t o_h1 = o_h0 + nslot  * SLAB_B;
  size_t o_u  = o_h1 + nslot  * SLAB_B;
  size_t o_xb = o_u  + nuslot * SLAB_B;
  int use_xb = (plain || ws_size >= o_xb + (size_t)TT * SLAB_B) ? 1 : 0;

  unsigned* flags = (unsigned*)ws;
  const u16* W0t = (const u16*)(ws + OFF_W0T);
  const u16* W1t = (const u16*)(ws + OFF_W1T);
  u16* h0r = (u16*)(ws + o_h0);
  u16* h1r = (u16*)(ws + o_h1);
  u16* ur  = (u16*)(ws + o_u);
  u16* xb  = (u16*)(ws + o_xb);

  zero_flags<<<192, 256, 0, stream>>>(flags);
  transpose_w<<<1024, 256, 0, stream>>>(W0, W1, (u16*)(ws + OFF_W0T));
  if (use_xb) xconv<<<32768, 256, 0, stream>>>(x, xb);

  (void)hipFuncSetAttribute((const void*)rnn_seq<false>,
                            hipFuncAttributeMaxDynamicSharedMemorySize, LDS_REQ);
  (void)hipFuncSetAttribute((const void*)rnn_seq<true>,
                            hipFuncAttributeMaxDynamicSharedMemorySize, LDS_REQ);

  void* args[12];
  args[0]  = (void*)&x;    args[1]  = (void*)&b0;   args[2]  = (void*)&b1;
  args[3]  = (void*)&out;  args[4]  = (void*)&flags;
  args[5]  = (void*)&W0t;  args[6]  = (void*)&W1t;
  args[7]  = (void*)&h0r;  args[8]  = (void*)&h1r;  args[9]  = (void*)&ur;
  args[10] = (void*)&xb;   args[11] = (void*)&use_xb;
  hipLaunchCooperativeKernel(plain ? (void*)rnn_seq<false> : (void*)rnn_seq<true>,
                             dim3(96), dim3(1024), args, LDS_REQ, stream);
}

// Round 4
// 4869.083 us; speedup vs baseline: 1.0042x; 1.0007x over previous
//
#include <hip/hip_runtime.h>
#include <cmath>

// ---------------------------------------------------------------------------
// 2-layer tanh RNN, B=64, T=512, D=H0=H1=1024. Persistent cooperative kernel.
// Round-8: SCOPE ISOLATION. Identical structure to round-7 (verified); the
// ONLY change is every inter-WG memory operation (flag polls, flag stores,
// ring loads/stores, U load) moves from __HIP_MEMORY_SCOPE_SYSTEM to
// __HIP_MEMORY_SCOPE_AGENT. Theory: on MI355X the Infinity Cache is not
// CPU-coherent, so SYSTEM-scope ops take their coherence point at HBM
// (~900-1100 cy/leg); AGENT scope (all we need: 8 XCDs of one GPU) can
// coherence-point at the shared L3 (~400-500 cy/leg). ~5-6 serial legs per
// step * 512 steps -> predicted ~1-1.6 ms saved if the theory holds.
// Groups (32 WGs each, cols split 32/WG):
//   G0: h0(t) = tanh(Wh0*h0(t-1) + U(t))                [K=1024]
//   G1: h1(t) = tanh(W1*[h1(t-1); h0(t)] + b1)          [K=2048]
//       (16 waves = 4 row-blocks x {h0-half, h1-half} x 2 K-slices)
//   G2: U(t)  = Wx*x(t) + b0   (free-runs ahead)        [K=1024]
// Sync: relaxed AGENT flags/data; producer order via __syncthreads'
// vmcnt(0) drain before the flag store (protocol verified rounds 2-4/6/7).
// ---------------------------------------------------------------------------

typedef unsigned short u16;
typedef unsigned int   u32;
typedef unsigned long long u64;
typedef __bf16 bf16x8 __attribute__((ext_vector_type(8)));
typedef u16    u16x8  __attribute__((ext_vector_type(8)));
typedef u16    u16x4  __attribute__((ext_vector_type(4)));
typedef float  f32x4  __attribute__((ext_vector_type(4)));

#define XSCOPE __HIP_MEMORY_SCOPE_AGENT

constexpr int BB = 64;
constexpr int TT = 512;
constexpr size_t SLOT   = (size_t)64 * 1024;   // elements per [64][1024] slab
constexpr size_t SLAB_B = SLOT * 2;            // 128 KB bf16 slab

constexpr size_t OFF_W0T = 262144;             // flags in [0, 256K)
constexpr size_t OFF_W1T = OFF_W0T + (size_t)1024 * 2048 * 2;
constexpr size_t OFF_R   = OFF_W1T + (size_t)1024 * 2048 * 2;

// LDS budget (dynamic): G1: 128K weights + 24K scr + 4K hch = 156K
//                       G0/G2: 64K weights + 32K scr        =  96K
constexpr int LDS_REQ = 159744;

__device__ inline u16 f2bf(float f) { return __builtin_bit_cast(u16, (__bf16)f); }
__device__ inline float bf2f(u16 v) { return (float)__builtin_bit_cast(__bf16, v); }
__device__ inline float fast_tanh(float x) {
  x = fminf(15.f, fmaxf(-15.f, x));
  float e = __expf(2.f * x);
  return (e - 1.f) * __builtin_amdgcn_rcpf(e + 1.f);
}

// ---------------------------------------------------------------- prep kernels
__global__ void zero_flags(unsigned* f) {
  int i = blockIdx.x * 256 + threadIdx.x;
  if (i < 3 * 512 * 32) f[i] = 0;
}

__global__ void transpose_w(const float* __restrict__ W0,
                            const float* __restrict__ W1,
                            u16* __restrict__ wt_base) {
  __shared__ float tile[64][65];
  int bi  = blockIdx.x;
  int mat = bi >> 9;
  int t   = bi & 511;
  int tk = t & 31, tn = t >> 5;
  const float* W = mat ? W1 : W0;
  u16* Wt = wt_base + (size_t)mat * 1024 * 2048;
  int K0 = tk * 64, N0 = tn * 64;
  int tid = threadIdx.x;
  {
    int c4 = (tid & 15) * 4;
    int r  = tid >> 4;
    for (int i = 0; i < 4; ++i) {
      int kl = r + i * 16;
      float4 v = *(const float4*)(W + (size_t)(K0 + kl) * 1024 + N0 + c4);
      tile[kl][c4 + 0] = v.x; tile[kl][c4 + 1] = v.y;
      tile[kl][c4 + 2] = v.z; tile[kl][c4 + 3] = v.w;
    }
  }
  __syncthreads();
  {
    int nl = tid >> 3;
    int kc = (tid & 7) * 8;
    for (int pass = 0; pass < 2; ++pass) {
      int n = nl + pass * 32;
      u16x8 o;
      #pragma unroll
      for (int z = 0; z < 8; ++z) o[z] = f2bf(tile[kc + z][n]);
      *(u16x8*)(Wt + (size_t)(N0 + n) * 2048 + K0 + kc) = o;
    }
  }
}

__global__ void xconv(const float* __restrict__ x, u16* __restrict__ xb) {
  int bi = blockIdx.x;               // 32768 = B*T
  int b = bi >> 9, t = bi & 511;
  const float* src = x + ((size_t)b * TT + t) * 1024;
  u16* dst = xb + ((size_t)t * BB + b) * 1024;
  int i = threadIdx.x * 4;
  float4 v = *(const float4*)(src + i);
  u16x4 o; o[0] = f2bf(v.x); o[1] = f2bf(v.y); o[2] = f2bf(v.z); o[3] = f2bf(v.w);
  *(u16x4*)(dst + i) = o;
}

// ------------------------------------------------------------------- sync ops
__device__ inline void poll1(unsigned* p) {
  while (__hip_atomic_load(p, __ATOMIC_RELAXED, XSCOPE) == 0u)
    __builtin_amdgcn_s_sleep(1);
}

// ------------------------------------------- pipelined A-fragment load + MFMA
template<bool COHA>
__device__ inline void load_a8(const u16* Abase, size_t aoff, bf16x8* a) {
  const u16* ap = Abase + aoff;
  #pragma unroll
  for (int ks = 0; ks < 8; ++ks) {
    if constexpr (COHA) {
      u64 lo = __hip_atomic_load((u64*)(ap + ks * 32),     __ATOMIC_RELAXED, XSCOPE);
      u64 hi = __hip_atomic_load((u64*)(ap + ks * 32 + 4), __ATOMIC_RELAXED, XSCOPE);
      union { u64 q2[2]; bf16x8 v; } un; un.q2[0] = lo; un.q2[1] = hi;
      a[ks] = un.v;
    } else {
      a[ks] = __builtin_bit_cast(bf16x8, *(const u16x8*)(ap + ks * 32));
    }
  }
}

__device__ inline void fma8(const bf16x8* a, const u16* bp,
                            int gbase, int n15, f32x4& acc0, f32x4& acc1) {
  #pragma unroll
  for (int ks = 0; ks < 8; ++ks) {
    int g = (gbase + 4 * ks) ^ n15;          // XOR-16B swizzled group
    bf16x8 b0 = __builtin_bit_cast(bf16x8, *(const u16x8*)(bp + g * 8));
    bf16x8 b1 = __builtin_bit_cast(bf16x8, *(const u16x8*)(bp + 16 * 1024 + g * 8));
    acc0 = __builtin_amdgcn_mfma_f32_16x16x32_bf16(a[ks], b0, acc0, 0, 0, 0);
    acc1 = __builtin_amdgcn_mfma_f32_16x16x32_bf16(a[ks], b1, acc1, 0, 0, 0);
  }
}

// ------------------------------------------------------------- main persistent
template<bool COH>
__global__ void __launch_bounds__(1024, 1)
rnn_seq(const float* __restrict__ x, const float* __restrict__ b0v,
        const float* __restrict__ b1v, float* __restrict__ out,
        unsigned* __restrict__ flags, const u16* __restrict__ W0t,
        const u16* __restrict__ W1t, u16* __restrict__ h0r,
        u16* __restrict__ h1r, u16* __restrict__ ur,
        const u16* __restrict__ xb, int use_xb) {
  constexpr int RMASK = COH ? 15 : 511;
  constexpr int UMASK = COH ? 31 : 511;
  constexpr int RING = 16, URING = 32;
  extern __shared__ u16 lds[];
  unsigned* fl_h0 = flags;
  unsigned* fl_h1 = flags + 512 * 32;
  unsigned* fl_u  = flags + 2 * 512 * 32;

  int wg = blockIdx.x, tid = threadIdx.x;
  int grp = wg >> 5, j = wg & 31;        // 0=L0, 1=L1, 2=U
  int n0 = j * 32;
  int lane = tid & 63, wave = tid >> 6;  // 16 waves
  int rb = wave & 3;                     // row-block
  int ksl = wave >> 2;                   // G0/G2: K-slice; G1: slice id
  int n15 = lane & 15, q = lane >> 4;
  int r0 = rb * 16;

  // LDS regions
  u16*   wlds = lds;
  float* scr  = (float*)((char*)lds + ((grp == 1) ? 131072 : 65536));
  u16*   hch  = (u16*)((char*)scr + 24576);   // G1 only

  // ---- persistent LDS weights, XOR-16B swizzle, [half][n][k]
  {
    const u16* Wt = (grp == 1) ? W1t : W0t;
    int nh = (grp == 1) ? 2 : 1;
    for (int h = 0; h < nh; ++h) {
      int kb = (grp == 1) ? h * 1024 : (grp == 2 ? 1024 : 0);
      for (int idx = tid; idx < 32 * 128; idx += 1024) {
        int n = idx >> 7, g = idx & 127;
        u16x8 v = *(const u16x8*)(Wt + (size_t)(n0 + n) * 2048 + kb + g * 8);
        *(u16x8*)(wlds + h * 32768 + n * 1024 + ((g ^ (n & 15)) * 8)) = v;
      }
    }
  }
  __syncthreads();

  const size_t aoff = (size_t)(r0 + n15) * 1024 + ksl * 256 + q * 8;  // G0/G2
  const int gbase = 32 * ksl + q;                                     // G0/G2
  const u16* bp0 = wlds + n15 * 1024;            // weights half 0
  const u16* bp1 = wlds + 32768 + n15 * 1024;    // weights half 1 (G1)

  // G1 half-split geometry: slice = wave>>2 (0..3); half 0 = h0(t) (bp1),
  // half 1 = h1(t-1) (bp0); each half split into 2 K-slices of 512.
  const int slice = wave >> 2;
  const int half  = slice >> 1;
  const int ksl2  = slice & 1;
  const size_t aoffS = (size_t)(r0 + n15) * 1024 + ksl2 * 512 + q * 8;
  const int gbaseS = 64 * ksl2 + q;
  const u16* bpH = half ? bp0 : bp1;

  // per-thread output-slot mapping (1 u32 = 2 cols per thread)
  const int sb  = tid >> 4;              // 0..63 (batch row)
  const int scc = (tid & 15) * 2;        // col pair base
  const int rbT = sb >> 4, rr = sb & 15;

  // biases
  float bia = 0.f, bib = 0.f;            // G1 (n15 mapping, slice0 epilogue)
  if (grp == 1) { bia = b1v[n0 + n15]; bib = b1v[n0 + n15 + 16]; }
  float2 b2x = {0.f, 0.f};               // G2 (per-thread col mapping)
  if (grp == 2) b2x = *(const float2*)&b0v[n0 + scc];

  // ---- G1 split-K helpers (3 slices write, slice0 sums -> hch)
  auto scr_write = [&](int s, const f32x4& a0, const f32x4& a1) {
    int base = ((rb * 3 + s - 1) * 2) * 256 + (q * 4) * 16 + n15;
    #pragma unroll
    for (int i = 0; i < 4; ++i) scr[base + i * 16] = a0[i];
    #pragma unroll
    for (int i = 0; i < 4; ++i) scr[base + 256 + i * 16] = a1[i];
  };
  auto scr_sum = [&](f32x4& a0, f32x4& a1) {
    #pragma unroll
    for (int s = 0; s < 3; ++s) {
      int base = ((rb * 3 + s) * 2) * 256 + (q * 4) * 16 + n15;
      #pragma unroll
      for (int i = 0; i < 4; ++i) a0[i] += scr[base + i * 16];
      #pragma unroll
      for (int i = 0; i < 4; ++i) a1[i] += scr[base + 256 + i * 16];
    }
  };

  // ---- G0/G2 all-wave split-K: every wave writes its slice; every thread
  // then sums its own 2 output columns. 32KB scr: [rb][ksl][rr][tile*256+c]
  auto scr_put = [&](const f32x4& a0, const f32x4& a1) {
    int base = rb * 2048 + ksl * 512 + (q * 4) * 16 + n15;
    #pragma unroll
    for (int i = 0; i < 4; ++i) scr[base + i * 16] = a0[i];
    #pragma unroll
    for (int i = 0; i < 4; ++i) scr[base + 256 + i * 16] = a1[i];
  };
  auto col_sum = [&](int c2) -> float {
    int base = rbT * 2048 + (c2 >> 4) * 256 + rr * 16 + (c2 & 15);
    return (scr[base] + scr[base + 512]) + (scr[base + 1024] + scr[base + 1536]);
  };

  const size_t FIN = (size_t)BB * TT * 1024;

  if (grp == 0) {            // ---- G0: h0(t) = tanh(Wh0*h0(t-1) + U(t))
    for (int t = 0; t < TT; ++t) {
      if (tid < 32)      { if (t > 0)            poll1(&fl_h0[(t - 1) * 32 + tid]); }
      else if (tid < 64) {                       poll1(&fl_u [t * 32 + (tid - 32)]); }
      else if (tid < 96) { if (COH && t >= RING) poll1(&fl_h1[(t - RING) * 32 + (tid - 64)]); }
      __syncthreads();                                   // B1
      bf16x8 a[8];
      if (t > 0) load_a8<COH>(h0r + (size_t)((t - 1) & RMASK) * SLOT, aoff, a);
      u32 uval;
      {  // own U word, coalesced 4 B/thread, issued in the load window
        const u32* up = (const u32*)(ur + (size_t)(t & UMASK) * SLOT + sb * 1024 + n0 + scc);
        uval = COH ? __hip_atomic_load((u32*)up, __ATOMIC_RELAXED, XSCOPE)
                   : *up;
      }
      f32x4 acc0 = {0.f, 0.f, 0.f, 0.f}, acc1 = acc0;
      if (t > 0) fma8(a, bp0, gbase, n15, acc0, acc1);
      scr_put(acc0, acc1);
      __syncthreads();                                   // B2
      float v0 = fast_tanh(col_sum(scc)     + bf2f((u16)(uval & 0xffffu)));
      float v1 = fast_tanh(col_sum(scc + 1) + bf2f((u16)(uval >> 16)));
      u32 pv = (u32)f2bf(v0) | ((u32)f2bf(v1) << 16);
      __hip_atomic_store((u32*)(h0r + (size_t)(t & RMASK) * SLOT + sb * 1024 + n0 + scc),
                         pv, __ATOMIC_RELAXED, XSCOPE);
      __syncthreads();                                   // B4: vmcnt(0) drain
      if (tid == 0)
        __hip_atomic_store(&fl_h0[t * 32 + j], 1u, __ATOMIC_RELAXED, XSCOPE);
      if (t == TT - 1) {   // final state (non-critical, after flag)
        float2 o; o.x = v0; o.y = v1;
        *(float2*)&out[FIN + (size_t)sb * 2048 + n0 + scc] = o;
      }
    }
  } else if (grp == 1) {     // ---- G1: h1(t) = tanh(W1*[h1(t-1); h0(t)] + b1)
    for (int t = 0; t < TT; ++t) {
      if (tid < 32)      { poll1(&fl_h0[t * 32 + tid]); }
      else if (tid < 64) { if (t > 0) poll1(&fl_h1[(t - 1) * 32 + (tid - 32)]); }
      __syncthreads();                                   // B1
      f32x4 acc0 = {0.f, 0.f, 0.f, 0.f}, acc1 = acc0;
      if (half == 0) {                 // h0(t) half, weights half 1
        bf16x8 a[16];
        const u16* s0 = h0r + (size_t)(t & RMASK) * SLOT;
        load_a8<COH>(s0, aoffS, a);
        load_a8<COH>(s0, aoffS + 256, a + 8);
        fma8(a,     bpH, gbaseS,      n15, acc0, acc1);
        fma8(a + 8, bpH, gbaseS + 32, n15, acc0, acc1);
      } else if (t > 0) {              // h1(t-1) half, weights half 0
        bf16x8 a[16];
        const u16* s1 = h1r + (size_t)((t - 1) & RMASK) * SLOT;
        load_a8<COH>(s1, aoffS, a);
        load_a8<COH>(s1, aoffS + 256, a + 8);
        fma8(a,     bpH, gbaseS,      n15, acc0, acc1);
        fma8(a + 8, bpH, gbaseS + 32, n15, acc0, acc1);
      }
      if (slice > 0) scr_write(slice, acc0, acc1);
      __syncthreads();                                   // B2
      if (slice == 0) {
        scr_sum(acc0, acc1);
        #pragma unroll
        for (int i = 0; i < 4; ++i) {
          int b = r0 + q * 4 + i;
          hch[b * 32 + n15]      = f2bf(fast_tanh(acc0[i] + bia));
          hch[b * 32 + n15 + 16] = f2bf(fast_tanh(acc1[i] + bib));
        }
      }
      __syncthreads();                                   // B3
      u32 pv = ((u32*)hch)[tid];
      __hip_atomic_store((u32*)(h1r + (size_t)(t & RMASK) * SLOT + sb * 1024 + n0 + scc),
                         pv, __ATOMIC_RELAXED, XSCOPE);
      __syncthreads();                                   // B4
      if (tid == 0)
        __hip_atomic_store(&fl_h1[t * 32 + j], 1u, __ATOMIC_RELAXED, XSCOPE);
      {  // out stores AFTER flag (off the critical drain), coalesced 8 B
        float2 o; o.x = bf2f((u16)(pv & 0xffffu)); o.y = bf2f((u16)(pv >> 16));
        __builtin_nontemporal_store(o.x, &out[((size_t)sb * TT + t) * 1024 + n0 + scc]);
        __builtin_nontemporal_store(o.y, &out[((size_t)sb * TT + t) * 1024 + n0 + scc + 1]);
        if (t == TT - 1)
          *(float2*)&out[FIN + (size_t)sb * 2048 + 1024 + n0 + scc] = o;
      }
    }
  } else {                   // ---- G2: U(t) = Wx*x(t) + b0 (free-runs)
    for (int t = 0; t < TT; ++t) {
      if (COH && t >= URING) {
        if (tid < 32) poll1(&fl_h0[(t - URING) * 32 + tid]);
      }
      __syncthreads();                                   // B1
      bf16x8 a[8];
      if (use_xb) {
        load_a8<false>(xb + (size_t)t * SLOT, aoff, a);
      } else {
        const float* Ap = x + ((size_t)(r0 + n15) * TT + t) * 1024 + ksl * 256 + q * 8;
        float4 f[16];
        #pragma unroll
        for (int ks = 0; ks < 8; ++ks) {
          f[2 * ks]     = *(const float4*)(Ap + ks * 32);
          f[2 * ks + 1] = *(const float4*)(Ap + ks * 32 + 4);
        }
        #pragma unroll
        for (int ks = 0; ks < 8; ++ks) {
          bf16x8 tv;
          tv[0] = (__bf16)f[2*ks].x;   tv[1] = (__bf16)f[2*ks].y;
          tv[2] = (__bf16)f[2*ks].z;   tv[3] = (__bf16)f[2*ks].w;
          tv[4] = (__bf16)f[2*ks+1].x; tv[5] = (__bf16)f[2*ks+1].y;
          tv[6] = (__bf16)f[2*ks+1].z; tv[7] = (__bf16)f[2*ks+1].w;
          a[ks] = tv;
        }
      }
      f32x4 acc0 = {0.f, 0.f, 0.f, 0.f}, acc1 = acc0;
      fma8(a, bp0, gbase, n15, acc0, acc1);
      scr_put(acc0, acc1);
      __syncthreads();                                   // B2
      float v0 = col_sum(scc)     + b2x.x;
      float v1 = col_sum(scc + 1) + b2x.y;
      u32 pv = (u32)f2bf(v0) | ((u32)f2bf(v1) << 16);
      __hip_atomic_store((u32*)(ur + (size_t)(t & UMASK) * SLOT + sb * 1024 + n0 + scc),
                         pv, __ATOMIC_RELAXED, XSCOPE);
      __syncthreads();                                   // B4
      if (tid == 0)
        __hip_atomic_store(&fl_u[t * 32 + j], 1u, __ATOMIC_RELAXED, XSCOPE);
    }
  }
}

// ------------------------------------------------------------------ host side
extern "C" void kernel_launch(void* const* d_in, const int* in_sizes, int n_in,
                              void* d_out, int out_size, void* d_ws, size_t ws_size,
                              hipStream_t stream) {
  const float* x  = (const float*)d_in[0];
  const float* W0 = (const float*)d_in[1];
  const float* b0 = (const float*)d_in[2];
  const float* W1 = (const float*)d_in[3];
  const float* b1 = (const float*)d_in[4];
  float* out = (float*)d_out;
  unsigned char* ws = (unsigned char*)d_ws;

  const size_t WS_PLAIN = OFF_R + 4ull * 512 * SLAB_B;            // ~277 MB
  bool plain = ws_size >= WS_PLAIN;
  size_t nslot  = plain ? 512 : 16;
  size_t nuslot = plain ? 512 : 32;
  size_t o_h0 = OFF_R;
  size_t o_h1 = o_h0 + nslot  * SLAB_B;
  size_t o_u  = o_h1 + nslot  * SLAB_B;
  size_t o_xb = o_u  + nuslot * SLAB_B;
  int use_xb = (plain || ws_size >= o_xb + (size_t)TT * SLAB_B) ? 1 : 0;

  unsigned* flags = (unsigned*)ws;
  const u16* W0t = (const u16*)(ws + OFF_W0T);
  const u16* W1t = (const u16*)(ws + OFF_W1T);
  u16* h0r = (u16*)(ws + o_h0);
  u16* h1r = (u16*)(ws + o_h1);
  u16* ur  = (u16*)(ws + o_u);
  u16* xb  = (u16*)(ws + o_xb);

  zero_flags<<<192, 256, 0, stream>>>(flags);
  transpose_w<<<1024, 256, 0, stream>>>(W0, W1, (u16*)(ws + OFF_W0T));
  if (use_xb) xconv<<<32768, 256, 0, stream>>>(x, xb);

  (void)hipFuncSetAttribute((const void*)rnn_seq<false>,
                            hipFuncAttributeMaxDynamicSharedMemorySize, LDS_REQ);
  (void)hipFuncSetAttribute((const void*)rnn_seq<true>,
                            hipFuncAttributeMaxDynamicSharedMemorySize, LDS_REQ);

  void* args[12];
  args[0]  = (void*)&x;    args[1]  = (void*)&b0;   args[2]  = (void*)&b1;
  args[3]  = (void*)&out;  args[4]  = (void*)&flags;
  args[5]  = (void*)&W0t;  args[6]  = (void*)&W1t;
  args[7]  = (void*)&h0r;  args[8]  = (void*)&h1r;  args[9]  = (void*)&ur;
  args[10] = (void*)&xb;   args[11] = (void*)&use_xb;
  hipLaunchCooperativeKernel(plain ? (void*)rnn_seq<false> : (void*)rnn_seq<true>,
                             dim3(96), dim3(1024), args, LDS_REQ, stream);
}